// Round 5
// baseline (478.778 us; speedup 1.0000x reference)
//
#include <hip/hip_runtime.h>
#include <hip/hip_bf16.h>

// MultiScaleAttentionPE — MI355X round 5
// Algebraic refactor: pe_l[i] = G_l[k_i] + q_i@WP_l + x_i@AP_l + cvec_l,
// G_l = pe_{l+1}@Ptop_l - xyzR@WP_l (small bf16 MFMA GEMM). Exact fp32 NN.

typedef __hip_bfloat16 bf16;
typedef unsigned short us;
typedef __attribute__((ext_vector_type(8))) short short8;
typedef __attribute__((ext_vector_type(4))) float float4v;

#define cN0 65536
#define cN1 16384
#define cN2 4096
#define cN3 1024
#define cN4 256

// canonical fp32 offsets (floats, relative to C)
#define OFF_WALL 196608
#define OFF_BALL 197376
#define OFF_W    197632   /* W_i = OFF_W + i*1024, b_i = +768 ; i=0 is level4 */
#define OFF_PB   202752   /* pb_i = OFF_PB + i*256 */

__device__ __forceinline__ float b2f(bf16 v) { return __bfloat162float(v); }
__device__ __forceinline__ us f2b(float v) {
    union { float f; unsigned u; } x; x.f = v;
    unsigned r = x.u + 0x7FFF + ((x.u >> 16) & 1);
    return (us)(r >> 16);
}
__device__ __forceinline__ float lo2f(unsigned u) { union { unsigned x; float f; } c; c.x = u << 16; return c.f; }

// ---------------- dtype detect (bf16 vs fp32 storage) ----------------
__global__ void detect_kernel(const unsigned short* __restrict__ raw, int* __restrict__ flag) {
    __shared__ int bad;
    if (threadIdx.x == 0) bad = 0;
    __syncthreads();
    for (int i = threadIdx.x; i < 1024; i += 256) {
        int e = (raw[i] >> 7) & 0xFF;
        if (e >= 138) atomicOr(&bad, 1);
    }
    __syncthreads();
    if (threadIdx.x == 0) flag[0] = bad ? 1 : 0;
}

// ---------------- canonicalize small float tensors to fp32 ----------------
// order: xyz, Wall, ball, [W,b] x5 (level4..level0), pb x5
struct CanonArgs { const void* src[18]; };

__global__ void canon_kernel(CanonArgs a, const int* __restrict__ flag, float* __restrict__ dst) {
    const int sizes[18] = {196608, 768, 256,
                           768, 256, 768, 256, 768, 256, 768, 256, 768, 256,
                           256, 256, 256, 256, 256};
    int fp32 = flag[0];
    int gid = blockIdx.x * 256 + threadIdx.x;
    int off = 0;
#pragma unroll
    for (int s = 0; s < 18; ++s) {
        int n = sizes[s];
        if (gid >= off && gid < off + n) {
            int local = gid - off;
            float v = fp32 ? ((const float*)a.src[s])[local]
                           : b2f(((const bf16*)a.src[s])[local]);
            dst[gid] = v;
        }
        off += n;
    }
}

// ---------------- per-level folded params: WP = W@Ptop, AP = Wall@Pbot,
// cvec = b@Ptop + ball@Pbot + pb ----------------
struct Pp { const void* P[5]; };

__global__ void prep_level(Pp pp, const int* __restrict__ flag, const float* __restrict__ C,
                           float* __restrict__ WPb, float* __restrict__ APb,
                           float* __restrict__ CVb) {
    __shared__ float sW[768], sb[256], sWa[768], sba[256];
    int l = blockIdx.x, tid = threadIdx.x;
    const float* Wf = C + OFF_W + l * 1024;
    for (int i = tid; i < 768; i += 256) { sW[i] = Wf[i]; sWa[i] = C[OFF_WALL + i]; }
    sb[tid] = Wf[768 + tid];
    sba[tid] = C[OFF_BALL + tid];
    __syncthreads();
    int fp32 = flag[0];
    const void* P = pp.P[l];
    int c = tid;
    float wp0 = 0, wp1 = 0, wp2 = 0, ap0 = 0, ap1 = 0, ap2 = 0, cv = 0;
    for (int k = 0; k < 256; ++k) {
        float p = fp32 ? ((const float*)P)[(size_t)k * 256 + c]
                       : b2f(((const bf16*)P)[(size_t)k * 256 + c]);
        wp0 = fmaf(sW[k], p, wp0);
        wp1 = fmaf(sW[256 + k], p, wp1);
        wp2 = fmaf(sW[512 + k], p, wp2);
        cv = fmaf(sb[k], p, cv);
    }
    for (int k = 0; k < 256; ++k) {
        float p = fp32 ? ((const float*)P)[(size_t)(256 + k) * 256 + c]
                       : b2f(((const bf16*)P)[(size_t)(256 + k) * 256 + c]);
        ap0 = fmaf(sWa[k], p, ap0);
        ap1 = fmaf(sWa[256 + k], p, ap1);
        ap2 = fmaf(sWa[512 + k], p, ap2);
        cv = fmaf(sba[k], p, cv);
    }
    WPb[l * 768 + c] = wp0; WPb[l * 768 + 256 + c] = wp1; WPb[l * 768 + 512 + c] = wp2;
    APb[l * 768 + c] = ap0; APb[l * 768 + 256 + c] = ap1; APb[l * 768 + 512 + c] = ap2;
    CVb[l * 256 + c] = cv + C[OFF_PB + l * 256 + c];
}

// ---------------- Ptop -> Ptop^T bf16 [n][k], k<256 ----------------
__global__ void prep_ptop(Pp pp, const int* __restrict__ flag, us* __restrict__ PTb) {
    __shared__ us t[64 * 68];
    int level = blockIdx.x, kb = blockIdx.y, nb = blockIdx.z;
    int fp32 = flag[0];
    const void* P = pp.P[level];
    int kk = threadIdx.x >> 2, j0 = (threadIdx.x & 3) * 16;
    int k = kb * 64 + kk;
#pragma unroll
    for (int j = 0; j < 16; ++j) {
        int n = nb * 64 + j0 + j;
        float v = fp32 ? ((const float*)P)[(size_t)k * 256 + n]
                       : b2f(((const bf16*)P)[(size_t)k * 256 + n]);
        t[kk * 68 + j0 + j] = f2b(v);
    }
    __syncthreads();
    int nn = threadIdx.x >> 2, kg = (threadIdx.x & 3) * 16;
    us* dst = PTb + (size_t)level * 65536 + (size_t)(nb * 64 + nn) * 256 + kb * 64 + kg;
#pragma unroll
    for (int j = 0; j < 16; ++j) dst[j] = t[(kg + j) * 68 + nn];
}

// ---------------- cls4 (fp32 exact) ----------------
__global__ void cls4a_kernel(const float* __restrict__ C, float* __restrict__ cls4) {
    __shared__ float px[256], py[256], pz[256];
    int t = threadIdx.x;
    px[t] = C[3 * t + 0]; py[t] = C[3 * t + 1]; pz[t] = C[3 * t + 2];
    __syncthreads();
    float w0 = C[OFF_WALL + t], w1 = C[OFF_WALL + 256 + t], w2 = C[OFF_WALL + 512 + t];
    float b = C[OFF_BALL + t];
    float best = -3.402823466e38f;
    for (int i = 0; i < 256; ++i) {
        float v = fmaf(pz[i], w2, fmaf(py[i], w1, px[i] * w0)) + b;
        best = fmaxf(best, v);
    }
    cls4[t] = best;
}

// cvecTot4[c] = cvec4[c] + sum_k cls4[k] * P4[k][c]
__global__ void cls4b_kernel(const void* __restrict__ P4, const int* __restrict__ flag,
                             const float* __restrict__ cls4, const float* __restrict__ CVb,
                             float* __restrict__ CT4) {
    __shared__ float cl[256];
    int c = threadIdx.x;
    cl[c] = cls4[c];
    __syncthreads();
    int fp32 = flag[0];
    float s = 0.f;
    for (int k = 0; k < 256; ++k) {
        float p = fp32 ? ((const float*)P4)[(size_t)k * 256 + c]
                       : b2f(((const bf16*)P4)[(size_t)k * 256 + c]);
        s = fmaf(cl[k], p, s);
    }
    CT4[c] = CVb[c] + s;
}

// ---------------- 1-NN argmin (fp32-exact, reference op order) ----------------
__global__ void nn_kernel(const float* __restrict__ xyzf, const int* __restrict__ idxQ,
                          const int* __restrict__ idxR, int nR, int* __restrict__ outK) {
    __shared__ __align__(16) float4 ref4[1024];
    __shared__ float redD[256];
    __shared__ int redI[256];
    int tid = threadIdx.x;
    int part = tid >> 6;
    int q = blockIdx.x * 64 + (tid & 63);
    int qi = idxQ[q];
    float qx = xyzf[3 * qi + 0];
    float qy = xyzf[3 * qi + 1];
    float qz = xyzf[3 * qi + 2];
    float q2 = (qx * qx + qy * qy) + qz * qz;
    float best = 3.402823466e38f;
    int bi = 0;
    for (int base = 0; base < nR; base += 1024) {
        int nt = min(1024, nR - base);
        __syncthreads();
        for (int t = tid; t < nt; t += 256) {
            int ri = idxR[base + t];
            float x = xyzf[3 * ri + 0];
            float y = xyzf[3 * ri + 1];
            float z = xyzf[3 * ri + 2];
            ref4[t] = make_float4(x, y, z, (x * x + y * y) + z * z);
        }
        __syncthreads();
        int seg = nt >> 2;
        int s0 = part * seg;
        for (int t = 0; t < seg; ++t) {
            float4 rp = ref4[s0 + t];
            float dot = (qx * rp.x + qy * rp.y) + qz * rp.z;
            float d = (q2 - 2.0f * dot) + rp.w;
            if (d < best) { best = d; bi = base + s0 + t; }
        }
    }
    redD[tid] = best;
    redI[tid] = bi;
    __syncthreads();
    if (part == 0) {
#pragma unroll
        for (int p = 1; p < 4; ++p) {
            float d = redD[tid + p * 64];
            int i2 = redI[tid + p * 64];
            if (d < best || (d == best && i2 < bi)) { best = d; bi = i2; }
        }
        outK[q] = bi;
    }
}

// ---------------- G build: G[j] = bf16( peB[j] @ Ptop - xyzR_j @ WP ) ----------------
// Block: 64 rows x 256 cols, 256 threads (4 waves of 64x64), K=256.
__global__ __launch_bounds__(256) void gbuild(
    const us* __restrict__ peB, const us* __restrict__ PT,
    const float* __restrict__ xyzf, const int* __restrict__ idxR,
    const float* __restrict__ WP, us* __restrict__ G) {
    __shared__ __align__(16) us A_lds[64 * 40];
    __shared__ __align__(16) us B_lds[256 * 40];
    __shared__ float rX[64][3];
    int tid = threadIdx.x;
    int row0 = blockIdx.x * 64;
    if (tid < 64) {
        int ri = idxR[row0 + tid];
        rX[tid][0] = xyzf[3 * ri]; rX[tid][1] = xyzf[3 * ri + 1]; rX[tid][2] = xyzf[3 * ri + 2];
    }
    int wave = tid >> 6, lane = tid & 63, quad = lane >> 4, l16 = lane & 15;
    int wc = wave * 64;
    int kk = quad * 8;

    float4v acc[4][4];
#pragma unroll
    for (int mt = 0; mt < 4; ++mt)
#pragma unroll
        for (int nt = 0; nt < 4; ++nt) acc[mt][nt] = (float4v){0.f, 0.f, 0.f, 0.f};

    for (int kt = 0; kt < 8; ++kt) {
        int ar = tid >> 2, ag = (tid & 3) * 8;
        *(uint4*)&A_lds[ar * 40 + ag] =
            *(const uint4*)(peB + (size_t)(row0 + ar) * 256 + kt * 32 + ag);
#pragma unroll
        for (int it = 0; it < 4; ++it) {
            int lin = it * 256 + tid;
            int n = lin >> 2, g = (lin & 3) * 8;
            *(uint4*)&B_lds[n * 40 + g] = *(const uint4*)(PT + (size_t)n * 256 + kt * 32 + g);
        }
        __syncthreads();
        short8 bfr[4];
#pragma unroll
        for (int nt = 0; nt < 4; ++nt)
            bfr[nt] = *(const short8*)&B_lds[(wc + nt * 16 + l16) * 40 + kk];
#pragma unroll
        for (int mt = 0; mt < 4; ++mt) {
            short8 af = *(const short8*)&A_lds[(mt * 16 + l16) * 40 + kk];
#pragma unroll
            for (int nt = 0; nt < 4; ++nt)
                acc[mt][nt] = __builtin_amdgcn_mfma_f32_16x16x32_bf16(af, bfr[nt], acc[mt][nt], 0, 0, 0);
        }
        __syncthreads();
    }
#pragma unroll
    for (int mt = 0; mt < 4; ++mt) {
#pragma unroll
        for (int nt = 0; nt < 4; ++nt) {
            int col = wc + nt * 16 + l16;
            float w0 = WP[col], w1 = WP[256 + col], w2 = WP[512 + col];
#pragma unroll
            for (int reg = 0; reg < 4; ++reg) {
                int row = mt * 16 + quad * 4 + reg;
                float val = acc[mt][nt][reg]
                          - (rX[row][0] * w0 + rX[row][1] * w1 + rX[row][2] * w2);
                G[(size_t)(row0 + row) * 256 + col] = f2b(val);
            }
        }
    }
}

// ---------------- epilogue: out[i] = G[k_i] + q_i@WP + x_i@AP + cvec ----------------
// 64 rows per block, 256 threads (one column each).
__global__ __launch_bounds__(256) void epi(
    const us* __restrict__ G, const int* __restrict__ kmap, const int* __restrict__ idxQ,
    const float* __restrict__ xyzf, const float* __restrict__ WP,
    const float* __restrict__ AP, const float* __restrict__ cvec,
    const int* __restrict__ flag, void* __restrict__ outv, size_t out_off,
    us* __restrict__ peOut) {
    __shared__ int kI[64];
    __shared__ float qv[64][3], xv[64][3];
    int tid = threadIdx.x;
    int row0 = blockIdx.x * 64;
    if (tid < 64) {
        int row = row0 + tid;
        kI[tid] = kmap ? kmap[row] : 0;
        int qi = idxQ ? idxQ[row] : row;
        qv[tid][0] = xyzf[3 * qi]; qv[tid][1] = xyzf[3 * qi + 1]; qv[tid][2] = xyzf[3 * qi + 2];
        xv[tid][0] = xyzf[3 * row]; xv[tid][1] = xyzf[3 * row + 1]; xv[tid][2] = xyzf[3 * row + 2];
    }
    __syncthreads();
    int c = tid;
    float w0 = WP[c], w1 = WP[256 + c], w2 = WP[512 + c];
    float a0 = AP[c], a1 = AP[256 + c], a2 = AP[512 + c];
    float cv = cvec[c];
    int fp32out = flag[0];
    for (int r = 0; r < 64; ++r) {
        float g = G ? lo2f((unsigned)G[(size_t)kI[r] * 256 + c]) : 0.f;
        float val = g + (qv[r][0] * w0 + qv[r][1] * w1 + qv[r][2] * w2)
                      + (xv[r][0] * a0 + xv[r][1] * a1 + xv[r][2] * a2) + cv;
        size_t idx = (size_t)(row0 + r) * 256 + c;
        if (fp32out) ((float*)outv)[out_off + idx] = val;
        else         ((bf16*)outv)[out_off + idx] = __float2bfloat16(val);
        if (peOut) peOut[idx] = f2b(val);
    }
}

extern "C" void kernel_launch(void* const* d_in, const int* in_sizes, int n_in,
                              void* d_out, int out_size, void* d_ws, size_t ws_size,
                              hipStream_t stream) {
    const int* idx0 = (const int*)d_in[1];
    const int* idx1 = (const int*)d_in[2];
    const int* idx2 = (const int*)d_in[3];
    const int* idx3 = (const int*)d_in[4];
    const int* idx4 = (const int*)d_in[5];

    // workspace layout
    float* ws = (float*)d_ws;
    int* flag = (int*)ws;                 // 64 floats reserved
    float* C = ws + 64;                   // canonical fp32 block (204032 floats)
    float* xyzf = C;
    float* WPb = C + 204032;              // 5 * 768
    float* APb = WPb + 5 * 768;           // 5 * 768
    float* CVb = APb + 5 * 768;           // 5 * 256
    float* CT4 = CVb + 5 * 256;           // 256
    float* cls4 = CT4 + 256;              // 256
    int* k34 = (int*)(cls4 + 256);
    int* k23 = k34 + 1024;
    int* k12 = k23 + 4096;
    us* PTb = (us*)(((uintptr_t)(k12 + 16384) + 15) & ~(uintptr_t)15);
    us* peB4 = PTb + 5 * 65536;           // 256*256
    us* peB3 = peB4 + 65536;              // 1024*256
    us* peB2 = peB3 + 262144;             // 4096*256
    us* peB1 = peB2 + 1048576;            // 16384*256
    us* G3 = peB1 + 4194304;              // 256*256
    us* G2 = G3 + 65536;                  // 1024*256
    us* G1 = G2 + 262144;                 // 4096*256
    us* G0 = G1 + 1048576;                // 16384*256

    detect_kernel<<<1, 256, 0, stream>>>((const unsigned short*)d_in[0], flag);

    CanonArgs ca;
    ca.src[0] = d_in[0];                  // xyz0
    ca.src[1] = d_in[6];                  // W_all
    ca.src[2] = d_in[7];                  // b_all
    for (int i = 0; i < 10; ++i) ca.src[3 + i] = d_in[8 + i];    // W4,b4..W0,b0
    ca.src[13] = d_in[19]; ca.src[14] = d_in[21]; ca.src[15] = d_in[23];
    ca.src[16] = d_in[25]; ca.src[17] = d_in[27];                // pb4..pb0
    canon_kernel<<<797, 256, 0, stream>>>(ca, flag, C);

    Pp pp;
    pp.P[0] = d_in[18]; pp.P[1] = d_in[20]; pp.P[2] = d_in[22];
    pp.P[3] = d_in[24]; pp.P[4] = d_in[26];

    prep_level<<<5, 256, 0, stream>>>(pp, flag, C, WPb, APb, CVb);
    prep_ptop<<<dim3(5, 4, 4), 256, 0, stream>>>(pp, flag, PTb);
    cls4a_kernel<<<1, 256, 0, stream>>>(C, cls4);
    cls4b_kernel<<<1, 256, 0, stream>>>(pp.P[0], flag, cls4, CVb, CT4);

    nn_kernel<<<cN3 / 64, 256, 0, stream>>>(xyzf, idx3, idx4, cN4, k34);
    nn_kernel<<<cN2 / 64, 256, 0, stream>>>(xyzf, idx2, idx3, cN3, k23);
    nn_kernel<<<cN1 / 64, 256, 0, stream>>>(xyzf, idx1, idx2, cN2, k12);

    const size_t o4 = 0;
    const size_t o3 = (size_t)cN4 * 256;
    const size_t o2 = o3 + (size_t)cN3 * 256;
    const size_t o1 = o2 + (size_t)cN2 * 256;
    const size_t o0 = o1 + (size_t)cN1 * 256;

    // level 4: no G
    epi<<<cN4 / 64, 256, 0, stream>>>(nullptr, nullptr, idx4, xyzf,
        WPb + 0 * 768, APb + 0 * 768, CT4, flag, d_out, o4, peB4);
    // level 3
    gbuild<<<cN4 / 64, 256, 0, stream>>>(peB4, PTb + 1 * 65536, xyzf, idx4,
        WPb + 1 * 768, G3);
    epi<<<cN3 / 64, 256, 0, stream>>>(G3, k34, idx3, xyzf,
        WPb + 1 * 768, APb + 1 * 768, CVb + 1 * 256, flag, d_out, o3, peB3);
    // level 2
    gbuild<<<cN3 / 64, 256, 0, stream>>>(peB3, PTb + 2 * 65536, xyzf, idx3,
        WPb + 2 * 768, G2);
    epi<<<cN2 / 64, 256, 0, stream>>>(G2, k23, idx2, xyzf,
        WPb + 2 * 768, APb + 2 * 768, CVb + 2 * 256, flag, d_out, o2, peB2);
    // level 1
    gbuild<<<cN2 / 64, 256, 0, stream>>>(peB2, PTb + 3 * 65536, xyzf, idx2,
        WPb + 3 * 768, G1);
    epi<<<cN1 / 64, 256, 0, stream>>>(G1, k12, idx1, xyzf,
        WPb + 3 * 768, APb + 3 * 768, CVb + 3 * 256, flag, d_out, o1, peB1);
    // level 0
    gbuild<<<cN1 / 64, 256, 0, stream>>>(peB1, PTb + 4 * 65536, xyzf, idx1,
        WPb + 4 * 768, G0);
    epi<<<cN0 / 64, 256, 0, stream>>>(G0, idx0, nullptr, xyzf,
        WPb + 4 * 768, APb + 4 * 768, CVb + 4 * 256, flag, d_out, o0, nullptr);
}

// Round 6
// 419.478 us; speedup vs baseline: 1.1414x; 1.1414x over previous
//
#include <hip/hip_runtime.h>
#include <hip/hip_bf16.h>

// MultiScaleAttentionPE — MI355X round 6
// r5 algebra (pe_l[i] = G_l[k_i] + q@WP + x@AP + cvec) with the parameter
// folding parallelized: two-phase reductions instead of 1280-thread serial
// kernels (r5's prep_level was 80 us at 0.2% occupancy).

typedef __hip_bfloat16 bf16;
typedef unsigned short us;
typedef __attribute__((ext_vector_type(8))) short short8;
typedef __attribute__((ext_vector_type(4))) float float4v;

#define cN0 65536
#define cN1 16384
#define cN2 4096
#define cN3 1024
#define cN4 256

// canonical fp32 offsets (floats, relative to C)
#define OFF_WALL 196608
#define OFF_BALL 197376
#define OFF_W    197632   /* W_i = OFF_W + i*1024, b_i = +768 ; i=0 is level4 */
#define OFF_PB   202752   /* pb_i = OFF_PB + i*256 */

__device__ __forceinline__ float b2f(bf16 v) { return __bfloat162float(v); }
__device__ __forceinline__ us f2b(float v) {
    union { float f; unsigned u; } x; x.f = v;
    unsigned r = x.u + 0x7FFF + ((x.u >> 16) & 1);
    return (us)(r >> 16);
}
__device__ __forceinline__ float lo2f(unsigned u) { union { unsigned x; float f; } c; c.x = u << 16; return c.f; }

// ---------------- dtype detect (bf16 vs fp32 storage) ----------------
__global__ void detect_kernel(const unsigned short* __restrict__ raw, int* __restrict__ flag) {
    __shared__ int bad;
    if (threadIdx.x == 0) bad = 0;
    __syncthreads();
    for (int i = threadIdx.x; i < 1024; i += 256) {
        int e = (raw[i] >> 7) & 0xFF;
        if (e >= 138) atomicOr(&bad, 1);
    }
    __syncthreads();
    if (threadIdx.x == 0) flag[0] = bad ? 1 : 0;
}

// ---------------- canonicalize small float tensors to fp32 ----------------
// order: xyz, Wall, ball, [W,b] x5 (level4..level0), pb x5
struct CanonArgs { const void* src[18]; };

__global__ void canon_kernel(CanonArgs a, const int* __restrict__ flag, float* __restrict__ dst) {
    const int sizes[18] = {196608, 768, 256,
                           768, 256, 768, 256, 768, 256, 768, 256, 768, 256,
                           256, 256, 256, 256, 256};
    int fp32 = flag[0];
    int gid = blockIdx.x * 256 + threadIdx.x;
    int off = 0;
#pragma unroll
    for (int s = 0; s < 18; ++s) {
        int n = sizes[s];
        if (gid >= off && gid < off + n) {
            int local = gid - off;
            float v = fp32 ? ((const float*)a.src[s])[local]
                           : b2f(((const bf16*)a.src[s])[local]);
            dst[gid] = v;
        }
        off += n;
    }
}

struct Pp { const void* P[5]; };

// ---------------- fold phase 1: per-(level, 32-k-chunk) partials ----------------
// chunks 0..7  : Ptop rows k=t*32..+31 weighted by W rows / b
// chunks 8..15 : Pbot rows weighted by Wall rows / ball
// partial layout: part[((l*16 + t)*4 + j)*256 + c], j = {w0,w1,w2,cv}
__global__ __launch_bounds__(256) void prep_partial(Pp pp, const int* __restrict__ flag,
                                                    const float* __restrict__ C,
                                                    float* __restrict__ part) {
    int l = blockIdx.x, t = blockIdx.y;
    int c = threadIdx.x;
    __shared__ float w0s[32], w1s[32], w2s[32], cvs[32];
    bool top = t < 8;
    int k0 = top ? t * 32 : (t - 8) * 32;
    if (threadIdx.x < 32) {
        int k = k0 + threadIdx.x;
        if (top) {
            const float* Wf = C + OFF_W + l * 1024;
            w0s[threadIdx.x] = Wf[k];
            w1s[threadIdx.x] = Wf[256 + k];
            w2s[threadIdx.x] = Wf[512 + k];
            cvs[threadIdx.x] = Wf[768 + k];
        } else {
            w0s[threadIdx.x] = C[OFF_WALL + k];
            w1s[threadIdx.x] = C[OFF_WALL + 256 + k];
            w2s[threadIdx.x] = C[OFF_WALL + 512 + k];
            cvs[threadIdx.x] = C[OFF_BALL + k];
        }
    }
    __syncthreads();
    const void* P = pp.P[l];
    int fp32 = flag[0];
    int krow0 = top ? k0 : 256 + k0;
    float s0 = 0, s1 = 0, s2 = 0, s3 = 0;
#pragma unroll 4
    for (int j = 0; j < 32; ++j) {
        float p = fp32 ? ((const float*)P)[(size_t)(krow0 + j) * 256 + c]
                       : b2f(((const bf16*)P)[(size_t)(krow0 + j) * 256 + c]);
        s0 = fmaf(w0s[j], p, s0);
        s1 = fmaf(w1s[j], p, s1);
        s2 = fmaf(w2s[j], p, s2);
        s3 = fmaf(cvs[j], p, s3);
    }
    float* dst = part + (((size_t)l * 16 + t) * 4) * 256;
    dst[c] = s0; dst[256 + c] = s1; dst[512 + c] = s2; dst[768 + c] = s3;
}

// ---------------- fold phase 2: reduce 16 partials per level ----------------
__global__ void prep_reduce(const float* __restrict__ part, const float* __restrict__ C,
                            float* __restrict__ WPb, float* __restrict__ APb,
                            float* __restrict__ CVb) {
    int l = blockIdx.x, c = threadIdx.x;
    float wp0 = 0, wp1 = 0, wp2 = 0, ap0 = 0, ap1 = 0, ap2 = 0, cv = 0;
    for (int t = 0; t < 8; ++t) {
        const float* d = part + (((size_t)l * 16 + t) * 4) * 256;
        wp0 += d[c]; wp1 += d[256 + c]; wp2 += d[512 + c]; cv += d[768 + c];
    }
    for (int t = 8; t < 16; ++t) {
        const float* d = part + (((size_t)l * 16 + t) * 4) * 256;
        ap0 += d[c]; ap1 += d[256 + c]; ap2 += d[512 + c]; cv += d[768 + c];
    }
    WPb[l * 768 + c] = wp0; WPb[l * 768 + 256 + c] = wp1; WPb[l * 768 + 512 + c] = wp2;
    APb[l * 768 + c] = ap0; APb[l * 768 + 256 + c] = ap1; APb[l * 768 + 512 + c] = ap2;
    CVb[l * 256 + c] = cv + C[OFF_PB + l * 256 + c];
}

// ---------------- Ptop -> Ptop^T bf16 [n][k], k<256 ----------------
__global__ void prep_ptop(Pp pp, const int* __restrict__ flag, us* __restrict__ PTb) {
    __shared__ us t[64 * 68];
    int level = blockIdx.x, kb = blockIdx.y, nb = blockIdx.z;
    int fp32 = flag[0];
    const void* P = pp.P[level];
    int kk = threadIdx.x >> 2, j0 = (threadIdx.x & 3) * 16;
    int k = kb * 64 + kk;
#pragma unroll
    for (int j = 0; j < 16; ++j) {
        int n = nb * 64 + j0 + j;
        float v = fp32 ? ((const float*)P)[(size_t)k * 256 + n]
                       : b2f(((const bf16*)P)[(size_t)k * 256 + n]);
        t[kk * 68 + j0 + j] = f2b(v);
    }
    __syncthreads();
    int nn = threadIdx.x >> 2, kg = (threadIdx.x & 3) * 16;
    us* dst = PTb + (size_t)level * 65536 + (size_t)(nb * 64 + nn) * 256 + kb * 64 + kg;
#pragma unroll
    for (int j = 0; j < 16; ++j) dst[j] = t[(kg + j) * 68 + nn];
}

// ---------------- cls4 column-max (fp32 exact) ----------------
__global__ void cls4a_kernel(const float* __restrict__ C, float* __restrict__ cls4) {
    __shared__ float px[256], py[256], pz[256];
    int t = threadIdx.x;
    px[t] = C[3 * t + 0]; py[t] = C[3 * t + 1]; pz[t] = C[3 * t + 2];
    __syncthreads();
    float w0 = C[OFF_WALL + t], w1 = C[OFF_WALL + 256 + t], w2 = C[OFF_WALL + 512 + t];
    float b = C[OFF_BALL + t];
    float best = -3.402823466e38f;
    for (int i = 0; i < 256; ++i) {
        float v = fmaf(pz[i], w2, fmaf(py[i], w1, px[i] * w0)) + b;
        best = fmaxf(best, v);
    }
    cls4[t] = best;
}

// cls4 @ P4top, two-phase
__global__ void cls4b_partial(const void* __restrict__ P4, const int* __restrict__ flag,
                              const float* __restrict__ cls4, float* __restrict__ cpart) {
    int t = blockIdx.x;          // 0..7
    int c = threadIdx.x;
    __shared__ float cl[32];
    if (threadIdx.x < 32) cl[threadIdx.x] = cls4[t * 32 + threadIdx.x];
    __syncthreads();
    int fp32 = flag[0];
    float s = 0.f;
#pragma unroll 4
    for (int j = 0; j < 32; ++j) {
        int k = t * 32 + j;
        float p = fp32 ? ((const float*)P4)[(size_t)k * 256 + c]
                       : b2f(((const bf16*)P4)[(size_t)k * 256 + c]);
        s = fmaf(cl[j], p, s);
    }
    cpart[t * 256 + c] = s;
}

__global__ void cls4b_reduce(const float* __restrict__ cpart, const float* __restrict__ CVb,
                             float* __restrict__ CT4) {
    int c = threadIdx.x;
    float s = 0.f;
    for (int t = 0; t < 8; ++t) s += cpart[t * 256 + c];
    CT4[c] = CVb[c] + s;
}

// ---------------- 1-NN argmin (fp32-exact, reference op order) ----------------
__global__ void nn_kernel(const float* __restrict__ xyzf, const int* __restrict__ idxQ,
                          const int* __restrict__ idxR, int nR, int* __restrict__ outK) {
    __shared__ __align__(16) float4 ref4[1024];
    __shared__ float redD[256];
    __shared__ int redI[256];
    int tid = threadIdx.x;
    int part = tid >> 6;
    int q = blockIdx.x * 64 + (tid & 63);
    int qi = idxQ[q];
    float qx = xyzf[3 * qi + 0];
    float qy = xyzf[3 * qi + 1];
    float qz = xyzf[3 * qi + 2];
    float q2 = (qx * qx + qy * qy) + qz * qz;
    float best = 3.402823466e38f;
    int bi = 0;
    for (int base = 0; base < nR; base += 1024) {
        int nt = min(1024, nR - base);
        __syncthreads();
        for (int t = tid; t < nt; t += 256) {
            int ri = idxR[base + t];
            float x = xyzf[3 * ri + 0];
            float y = xyzf[3 * ri + 1];
            float z = xyzf[3 * ri + 2];
            ref4[t] = make_float4(x, y, z, (x * x + y * y) + z * z);
        }
        __syncthreads();
        int seg = nt >> 2;
        int s0 = part * seg;
        for (int t = 0; t < seg; ++t) {
            float4 rp = ref4[s0 + t];
            float dot = (qx * rp.x + qy * rp.y) + qz * rp.z;
            float d = (q2 - 2.0f * dot) + rp.w;
            if (d < best) { best = d; bi = base + s0 + t; }
        }
    }
    redD[tid] = best;
    redI[tid] = bi;
    __syncthreads();
    if (part == 0) {
#pragma unroll
        for (int p = 1; p < 4; ++p) {
            float d = redD[tid + p * 64];
            int i2 = redI[tid + p * 64];
            if (d < best || (d == best && i2 < bi)) { best = d; bi = i2; }
        }
        outK[q] = bi;
    }
}

// ---------------- G build: G[j] = bf16( peB[j] @ Ptop - xyzR_j @ WP ) ----------------
// Block: 64 rows x 256 cols, 256 threads (4 waves of 64x64), K=256.
__global__ __launch_bounds__(256) void gbuild(
    const us* __restrict__ peB, const us* __restrict__ PT,
    const float* __restrict__ xyzf, const int* __restrict__ idxR,
    const float* __restrict__ WP, us* __restrict__ G) {
    __shared__ __align__(16) us A_lds[64 * 40];
    __shared__ __align__(16) us B_lds[256 * 40];
    __shared__ float rX[64][3];
    int tid = threadIdx.x;
    int row0 = blockIdx.x * 64;
    if (tid < 64) {
        int ri = idxR[row0 + tid];
        rX[tid][0] = xyzf[3 * ri]; rX[tid][1] = xyzf[3 * ri + 1]; rX[tid][2] = xyzf[3 * ri + 2];
    }
    int wave = tid >> 6, lane = tid & 63, quad = lane >> 4, l16 = lane & 15;
    int wc = wave * 64;
    int kk = quad * 8;

    float4v acc[4][4];
#pragma unroll
    for (int mt = 0; mt < 4; ++mt)
#pragma unroll
        for (int nt = 0; nt < 4; ++nt) acc[mt][nt] = (float4v){0.f, 0.f, 0.f, 0.f};

    for (int kt = 0; kt < 8; ++kt) {
        int ar = tid >> 2, ag = (tid & 3) * 8;
        *(uint4*)&A_lds[ar * 40 + ag] =
            *(const uint4*)(peB + (size_t)(row0 + ar) * 256 + kt * 32 + ag);
#pragma unroll
        for (int it = 0; it < 4; ++it) {
            int lin = it * 256 + tid;
            int n = lin >> 2, g = (lin & 3) * 8;
            *(uint4*)&B_lds[n * 40 + g] = *(const uint4*)(PT + (size_t)n * 256 + kt * 32 + g);
        }
        __syncthreads();
        short8 bfr[4];
#pragma unroll
        for (int nt = 0; nt < 4; ++nt)
            bfr[nt] = *(const short8*)&B_lds[(wc + nt * 16 + l16) * 40 + kk];
#pragma unroll
        for (int mt = 0; mt < 4; ++mt) {
            short8 af = *(const short8*)&A_lds[(mt * 16 + l16) * 40 + kk];
#pragma unroll
            for (int nt = 0; nt < 4; ++nt)
                acc[mt][nt] = __builtin_amdgcn_mfma_f32_16x16x32_bf16(af, bfr[nt], acc[mt][nt], 0, 0, 0);
        }
        __syncthreads();
    }
#pragma unroll
    for (int mt = 0; mt < 4; ++mt) {
#pragma unroll
        for (int nt = 0; nt < 4; ++nt) {
            int col = wc + nt * 16 + l16;
            float w0 = WP[col], w1 = WP[256 + col], w2 = WP[512 + col];
#pragma unroll
            for (int reg = 0; reg < 4; ++reg) {
                int row = mt * 16 + quad * 4 + reg;
                float val = acc[mt][nt][reg]
                          - (rX[row][0] * w0 + rX[row][1] * w1 + rX[row][2] * w2);
                G[(size_t)(row0 + row) * 256 + col] = f2b(val);
            }
        }
    }
}

// ---------------- epilogue: out[i] = G[k_i] + q_i@WP + x_i@AP + cvec ----------------
__global__ __launch_bounds__(256) void epi(
    const us* __restrict__ G, const int* __restrict__ kmap, const int* __restrict__ idxQ,
    const float* __restrict__ xyzf, const float* __restrict__ WP,
    const float* __restrict__ AP, const float* __restrict__ cvec,
    const int* __restrict__ flag, void* __restrict__ outv, size_t out_off,
    us* __restrict__ peOut) {
    __shared__ int kI[64];
    __shared__ float qv[64][3], xv[64][3];
    int tid = threadIdx.x;
    int row0 = blockIdx.x * 64;
    if (tid < 64) {
        int row = row0 + tid;
        kI[tid] = kmap ? kmap[row] : 0;
        int qi = idxQ ? idxQ[row] : row;
        qv[tid][0] = xyzf[3 * qi]; qv[tid][1] = xyzf[3 * qi + 1]; qv[tid][2] = xyzf[3 * qi + 2];
        xv[tid][0] = xyzf[3 * row]; xv[tid][1] = xyzf[3 * row + 1]; xv[tid][2] = xyzf[3 * row + 2];
    }
    __syncthreads();
    int c = tid;
    float w0 = WP[c], w1 = WP[256 + c], w2 = WP[512 + c];
    float a0 = AP[c], a1 = AP[256 + c], a2 = AP[512 + c];
    float cv = cvec[c];
    int fp32out = flag[0];
    for (int r = 0; r < 64; ++r) {
        float g = G ? lo2f((unsigned)G[(size_t)kI[r] * 256 + c]) : 0.f;
        float val = g + (qv[r][0] * w0 + qv[r][1] * w1 + qv[r][2] * w2)
                      + (xv[r][0] * a0 + xv[r][1] * a1 + xv[r][2] * a2) + cv;
        size_t idx = (size_t)(row0 + r) * 256 + c;
        if (fp32out) ((float*)outv)[out_off + idx] = val;
        else         ((bf16*)outv)[out_off + idx] = __float2bfloat16(val);
        if (peOut) peOut[idx] = f2b(val);
    }
}

extern "C" void kernel_launch(void* const* d_in, const int* in_sizes, int n_in,
                              void* d_out, int out_size, void* d_ws, size_t ws_size,
                              hipStream_t stream) {
    const int* idx0 = (const int*)d_in[1];
    const int* idx1 = (const int*)d_in[2];
    const int* idx2 = (const int*)d_in[3];
    const int* idx3 = (const int*)d_in[4];
    const int* idx4 = (const int*)d_in[5];

    // workspace layout
    float* ws = (float*)d_ws;
    int* flag = (int*)ws;                 // 64 floats reserved
    float* C = ws + 64;                   // canonical fp32 block (204032 floats)
    float* xyzf = C;
    float* WPb = C + 204032;              // 5 * 768
    float* APb = WPb + 5 * 768;           // 5 * 768
    float* CVb = APb + 5 * 768;           // 5 * 256
    float* CT4 = CVb + 5 * 256;           // 256
    float* cls4 = CT4 + 256;              // 256
    float* part = cls4 + 256;             // 5*16*4*256 = 81920
    float* cpart = part + 81920;          // 8*256 = 2048
    int* k34 = (int*)(cpart + 2048);
    int* k23 = k34 + 1024;
    int* k12 = k23 + 4096;
    us* PTb = (us*)(((uintptr_t)(k12 + 16384) + 15) & ~(uintptr_t)15);
    us* peB4 = PTb + 5 * 65536;           // 256*256
    us* peB3 = peB4 + 65536;              // 1024*256
    us* peB2 = peB3 + 262144;             // 4096*256
    us* peB1 = peB2 + 1048576;            // 16384*256
    us* G3 = peB1 + 4194304;              // 256*256
    us* G2 = G3 + 65536;                  // 1024*256
    us* G1 = G2 + 262144;                 // 4096*256
    us* G0 = G1 + 1048576;                // 16384*256

    detect_kernel<<<1, 256, 0, stream>>>((const unsigned short*)d_in[0], flag);

    CanonArgs ca;
    ca.src[0] = d_in[0];                  // xyz0
    ca.src[1] = d_in[6];                  // W_all
    ca.src[2] = d_in[7];                  // b_all
    for (int i = 0; i < 10; ++i) ca.src[3 + i] = d_in[8 + i];    // W4,b4..W0,b0
    ca.src[13] = d_in[19]; ca.src[14] = d_in[21]; ca.src[15] = d_in[23];
    ca.src[16] = d_in[25]; ca.src[17] = d_in[27];                // pb4..pb0
    canon_kernel<<<797, 256, 0, stream>>>(ca, flag, C);

    Pp pp;
    pp.P[0] = d_in[18]; pp.P[1] = d_in[20]; pp.P[2] = d_in[22];
    pp.P[3] = d_in[24]; pp.P[4] = d_in[26];

    prep_partial<<<dim3(5, 16), 256, 0, stream>>>(pp, flag, C, part);
    prep_reduce<<<5, 256, 0, stream>>>(part, C, WPb, APb, CVb);
    prep_ptop<<<dim3(5, 4, 4), 256, 0, stream>>>(pp, flag, PTb);
    cls4a_kernel<<<1, 256, 0, stream>>>(C, cls4);
    cls4b_partial<<<8, 256, 0, stream>>>(pp.P[0], flag, cls4, cpart);
    cls4b_reduce<<<1, 256, 0, stream>>>(cpart, CVb, CT4);

    nn_kernel<<<cN3 / 64, 256, 0, stream>>>(xyzf, idx3, idx4, cN4, k34);
    nn_kernel<<<cN2 / 64, 256, 0, stream>>>(xyzf, idx2, idx3, cN3, k23);
    nn_kernel<<<cN1 / 64, 256, 0, stream>>>(xyzf, idx1, idx2, cN2, k12);

    const size_t o4 = 0;
    const size_t o3 = (size_t)cN4 * 256;
    const size_t o2 = o3 + (size_t)cN3 * 256;
    const size_t o1 = o2 + (size_t)cN2 * 256;
    const size_t o0 = o1 + (size_t)cN1 * 256;

    // level 4: no G
    epi<<<cN4 / 64, 256, 0, stream>>>(nullptr, nullptr, idx4, xyzf,
        WPb + 0 * 768, APb + 0 * 768, CT4, flag, d_out, o4, peB4);
    // level 3
    gbuild<<<cN4 / 64, 256, 0, stream>>>(peB4, PTb + 1 * 65536, xyzf, idx4,
        WPb + 1 * 768, G3);
    epi<<<cN3 / 64, 256, 0, stream>>>(G3, k34, idx3, xyzf,
        WPb + 1 * 768, APb + 1 * 768, CVb + 1 * 256, flag, d_out, o3, peB3);
    // level 2
    gbuild<<<cN3 / 64, 256, 0, stream>>>(peB3, PTb + 2 * 65536, xyzf, idx3,
        WPb + 2 * 768, G2);
    epi<<<cN2 / 64, 256, 0, stream>>>(G2, k23, idx2, xyzf,
        WPb + 2 * 768, APb + 2 * 768, CVb + 2 * 256, flag, d_out, o2, peB2);
    // level 1
    gbuild<<<cN2 / 64, 256, 0, stream>>>(peB2, PTb + 3 * 65536, xyzf, idx2,
        WPb + 3 * 768, G1);
    epi<<<cN1 / 64, 256, 0, stream>>>(G1, k12, idx1, xyzf,
        WPb + 3 * 768, APb + 3 * 768, CVb + 3 * 256, flag, d_out, o1, peB1);
    // level 0
    gbuild<<<cN1 / 64, 256, 0, stream>>>(peB1, PTb + 4 * 65536, xyzf, idx1,
        WPb + 4 * 768, G0);
    epi<<<cN0 / 64, 256, 0, stream>>>(G0, idx0, nullptr, xyzf,
        WPb + 4 * 768, APb + 4 * 768, CVb + 4 * 256, flag, d_out, o0, nullptr);
}